// Round 1
// baseline (187214.075 us; speedup 1.0000x reference)
//
#include <hip/hip_runtime.h>
#include <math.h>

#define B_ 32
#define N_ 1024
#define C_ 512
#define H_ 256
#define V_ 50
#define T_ 501
#define CV_ 562   // C + V

__device__ __forceinline__ float fast_rcp(float x) { return __builtin_amdgcn_rcpf(x); }
__device__ __forceinline__ float fast_tanh(float x) {
  float e = __expf(2.0f * x);
  return 1.0f - 2.0f * fast_rcp(e + 1.0f);
}
__device__ __forceinline__ float fast_sigmoid(float x) {
  return fast_rcp(1.0f + __expf(-x));
}

// ---------------- feat_proj GEMM: FP[m][h] = sum_c A[m][c] * W[h][c] ----------------
// A: [32768][512] features, W: [256][512] w_i2h, FP: [32768][256]
__global__ __launch_bounds__(256) void fp_gemm(const float* __restrict__ A,
                                               const float* __restrict__ W,
                                               float* __restrict__ FP) {
  __shared__ __align__(16) float As[16][68];
  __shared__ __align__(16) float Ws[16][68];
  const int t = threadIdx.x;
  const int m0 = blockIdx.x * 64;
  const int h0 = blockIdx.y * 64;
  const int lr = t & 63;   // staging row within tile
  const int kg = t >> 6;   // 0..3 -> which 4 k's this wave stages
  const int tx = t & 15, ty = t >> 4;
  float acc[4][4] = {};
  for (int k0 = 0; k0 < C_; k0 += 16) {
    float4 av = *(const float4*)&A[(size_t)(m0 + lr) * C_ + k0 + kg * 4];
    float4 wv = *(const float4*)&W[(size_t)(h0 + lr) * C_ + k0 + kg * 4];
    As[kg*4+0][lr] = av.x; As[kg*4+1][lr] = av.y; As[kg*4+2][lr] = av.z; As[kg*4+3][lr] = av.w;
    Ws[kg*4+0][lr] = wv.x; Ws[kg*4+1][lr] = wv.y; Ws[kg*4+2][lr] = wv.z; Ws[kg*4+3][lr] = wv.w;
    __syncthreads();
#pragma unroll
    for (int kk = 0; kk < 16; ++kk) {
      float4 a = *(const float4*)&As[kk][ty * 4];
      float4 w = *(const float4*)&Ws[kk][tx * 4];
      acc[0][0] += a.x*w.x; acc[0][1] += a.x*w.y; acc[0][2] += a.x*w.z; acc[0][3] += a.x*w.w;
      acc[1][0] += a.y*w.x; acc[1][1] += a.y*w.y; acc[1][2] += a.y*w.z; acc[1][3] += a.y*w.w;
      acc[2][0] += a.z*w.x; acc[2][1] += a.z*w.y; acc[2][2] += a.z*w.z; acc[2][3] += a.z*w.w;
      acc[3][0] += a.w*w.x; acc[3][1] += a.w*w.y; acc[3][2] += a.w*w.z; acc[3][3] += a.w*w.w;
    }
    __syncthreads();
  }
#pragma unroll
  for (int i = 0; i < 4; ++i) {
    float4 o; o.x = acc[i][0]; o.y = acc[i][1]; o.z = acc[i][2]; o.w = acc[i][3];
    *(float4*)&FP[(size_t)(m0 + ty*4 + i) * H_ + h0 + tx*4] = o;
  }
}

// ---------------- init: h=0, pp=b_h2h (h0=0), pre=0, cnt=0 ----------------
__global__ void init_kernel(const float* __restrict__ b_h2h, float* __restrict__ h,
                            float* __restrict__ pp, int* __restrict__ pre,
                            int* __restrict__ cnt) {
  int i = blockIdx.x * blockDim.x + threadIdx.x;
  if (i < B_ * H_) { h[i] = 0.0f; pp[i] = b_h2h[i & (H_ - 1)]; }
  if (i < B_) pre[i] = 0;
  if (i < T_ * B_) cnt[i] = 0;
}

// ---------------- one decode step, fused ----------------
// grid = 1024 blocks (32 per b), block = 256 threads (4 waves)
__global__ __launch_bounds__(256) void step_kernel(
    int tstep,
    const float* __restrict__ feat, const float* __restrict__ fp,
    const float* __restrict__ w_score,
    const float* __restrict__ w_gru_ih, const float* __restrict__ w_gru_hh,
    const float* __restrict__ b_gru_ih, const float* __restrict__ b_gru_hh,
    const float* __restrict__ w_s1, const float* __restrict__ b_s1,
    const float* __restrict__ w_s2, const float* __restrict__ b_s2,
    const float* __restrict__ w_h2h, const float* __restrict__ b_h2h,
    float* __restrict__ h, float* __restrict__ pp, int* __restrict__ pre,
    float* __restrict__ part_ctx, float* __restrict__ part_l,
    int* __restrict__ cnt, float* __restrict__ out) {
  __shared__ __align__(16) float lds_ctx[4 * C_];  // per-wave partial ctx; reused as ctx in D
  __shared__ float lds_l[4];
  __shared__ __align__(16) float sh[H_];
  __shared__ __align__(16) float shn[H_];
  __shared__ __align__(16) float ss1[H_];
  __shared__ float sst[64];
  __shared__ int sflag;

  const int t = threadIdx.x;
  const int wv = t >> 6;
  const int lane = t & 63;
  const int b = blockIdx.x >> 5;
  const int chunk = blockIdx.x & 31;

  // ================= BC phase: scores -> exp -> weighted feature partials =================
  float4 ppr = *(const float4*)&pp[b * H_ + lane * 4];
  float4 wsr = *(const float4*)&w_score[lane * 4];
  float aA0 = 0.f, aA1 = 0.f, aA2 = 0.f, aA3 = 0.f;
  float aB0 = 0.f, aB1 = 0.f, aB2 = 0.f, aB3 = 0.f;
  float lacc = 0.f;
  const float* fpb = fp + (size_t)b * N_ * H_;
  const float* fb  = feat + (size_t)b * N_ * C_;
  const int n0 = chunk * 32 + wv * 8;
#pragma unroll 2
  for (int i = 0; i < 8; ++i) {
    const int n = n0 + i;
    float4 v = *(const float4*)&fpb[(size_t)n * H_ + lane * 4];
    float s = fast_tanh(v.x + ppr.x) * wsr.x + fast_tanh(v.y + ppr.y) * wsr.y
            + fast_tanh(v.z + ppr.z) * wsr.z + fast_tanh(v.w + ppr.w) * wsr.w;
#pragma unroll
    for (int off = 32; off > 0; off >>= 1) s += __shfl_xor(s, off);
    float p = __expf(s);   // |s| <= sum|w_score| ~ 10 -> safe without max-subtraction
    lacc += p;
    const float* frow = &fb[(size_t)n * C_ + lane * 8];
    float4 fa = *(const float4*)frow;
    float4 fc = *(const float4*)(frow + 4);
    aA0 += p * fa.x; aA1 += p * fa.y; aA2 += p * fa.z; aA3 += p * fa.w;
    aB0 += p * fc.x; aB1 += p * fc.y; aB2 += p * fc.z; aB3 += p * fc.w;
  }
  {
    float4 o0; o0.x = aA0; o0.y = aA1; o0.z = aA2; o0.w = aA3;
    float4 o1; o1.x = aB0; o1.y = aB1; o1.z = aB2; o1.w = aB3;
    *(float4*)&lds_ctx[wv * C_ + lane * 8] = o0;
    *(float4*)&lds_ctx[wv * C_ + lane * 8 + 4] = o1;
  }
  if (lane == 0) lds_l[wv] = lacc;
  __syncthreads();
  // block-combine the 4 waves, write per-block partial
  {
    float c0 = lds_ctx[t] + lds_ctx[C_ + t] + lds_ctx[2 * C_ + t] + lds_ctx[3 * C_ + t];
    float c1 = lds_ctx[t + 256] + lds_ctx[C_ + t + 256] + lds_ctx[2 * C_ + t + 256] + lds_ctx[3 * C_ + t + 256];
    float* pc = &part_ctx[((size_t)b * 32 + chunk) * C_];
    pc[t] = c0;
    pc[t + 256] = c1;
    if (t == 0) part_l[b * 32 + chunk] = lds_l[0] + lds_l[1] + lds_l[2] + lds_l[3];
  }
  __threadfence();
  __syncthreads();
  if (t == 0) sflag = atomicAdd(&cnt[tstep * B_ + b], 1);
  __syncthreads();
  if (sflag != 31) return;   // only the last-arriving block for this b continues
  __threadfence();           // acquire: make other blocks' partials visible

  // ================= D phase: combine -> GRU -> struct -> argmax -> out =================
  float lt = 0.f;
#pragma unroll 8
  for (int k = 0; k < 32; ++k) lt += part_l[b * 32 + k];
  const float invl = 1.0f / lt;
  float d0 = 0.f, d1 = 0.f;
#pragma unroll 4
  for (int k = 0; k < 32; ++k) {
    const float* q = &part_ctx[((size_t)b * 32 + k) * C_];
    d0 += q[t];
    d1 += q[t + 256];
  }
  float* sctx = lds_ctx;   // reuse (old contents consumed before ticket sync)
  sctx[t] = d0 * invl;
  sctx[t + 256] = d1 * invl;
  const float h_old = h[b * H_ + t];
  sh[t] = h_old;
  __syncthreads();

  // GRU: thread t owns rows t, t+256, t+512 of w_gru_ih / w_gru_hh
  const int prev = pre[b];
  const float* wr = w_gru_ih + (size_t)t * CV_;
  const float* wz = w_gru_ih + (size_t)(t + 256) * CV_;
  const float* wn = w_gru_ih + (size_t)(t + 512) * CV_;
  float gr = b_gru_ih[t]       + wr[C_ + prev];
  float gz = b_gru_ih[t + 256] + wz[C_ + prev];
  float gn = b_gru_ih[t + 512] + wn[C_ + prev];
#pragma unroll 8
  for (int c = 0; c < C_; c += 2) {   // float2: rows of w_gru_ih are only 8B-aligned (562 stride)
    float2 xc = *(const float2*)&sctx[c];
    float2 a  = *(const float2*)&wr[c];
    float2 bb = *(const float2*)&wz[c];
    float2 cc = *(const float2*)&wn[c];
    gr += a.x * xc.x + a.y * xc.y;
    gz += bb.x * xc.x + bb.y * xc.y;
    gn += cc.x * xc.x + cc.y * xc.y;
  }
  const float* ur = w_gru_hh + (size_t)t * H_;
  const float* uz = w_gru_hh + (size_t)(t + 256) * H_;
  const float* un = w_gru_hh + (size_t)(t + 512) * H_;
  float hr = b_gru_hh[t], hz = b_gru_hh[t + 256], hn2 = b_gru_hh[t + 512];
#pragma unroll 4
  for (int c = 0; c < H_; c += 4) {
    float4 hv = *(const float4*)&sh[c];
    float4 a  = *(const float4*)&ur[c];
    float4 bb = *(const float4*)&uz[c];
    float4 cc = *(const float4*)&un[c];
    hr  += a.x*hv.x + a.y*hv.y + a.z*hv.z + a.w*hv.w;
    hz  += bb.x*hv.x + bb.y*hv.y + bb.z*hv.z + bb.w*hv.w;
    hn2 += cc.x*hv.x + cc.y*hv.y + cc.z*hv.z + cc.w*hv.w;
  }
  const float r = fast_sigmoid(gr + hr);
  const float z = fast_sigmoid(gz + hz);
  const float nn = fast_tanh(gn + r * hn2);
  const float hnew = (1.0f - z) * nn + z * h_old;
  h[b * H_ + t] = hnew;
  shn[t] = hnew;
  __syncthreads();

  // s1 = hnew @ w_s1.T + b_s1 ; pp_next = hnew @ w_h2h.T + b_h2h
  {
    const float* w1 = w_s1 + (size_t)t * H_;
    const float* wh = w_h2h + (size_t)t * H_;
    float s1v = b_s1[t], ppv = b_h2h[t];
#pragma unroll 4
    for (int c = 0; c < H_; c += 4) {
      float4 hv = *(const float4*)&shn[c];
      float4 a  = *(const float4*)&w1[c];
      float4 bb = *(const float4*)&wh[c];
      s1v += a.x*hv.x + a.y*hv.y + a.z*hv.z + a.w*hv.w;
      ppv += bb.x*hv.x + bb.y*hv.y + bb.z*hv.z + bb.w*hv.w;
    }
    pp[b * H_ + t] = ppv;
    ss1[t] = s1v;
  }
  __syncthreads();

  if (t < V_) {
    const float* w2 = w_s2 + (size_t)t * H_;
    float sv = b_s2[t];
#pragma unroll 4
    for (int c = 0; c < H_; c += 4) {
      float4 hv = *(const float4*)&ss1[c];
      float4 a  = *(const float4*)&w2[c];
      sv += a.x*hv.x + a.y*hv.y + a.z*hv.z + a.w*hv.w;
    }
    sst[t] = sv;
  }
  __syncthreads();

  if (wv == 0) {
    float val = (lane < V_) ? sst[lane] : -INFINITY;
    float m = val;
#pragma unroll
    for (int off = 32; off > 0; off >>= 1) m = fmaxf(m, __shfl_xor(m, off));
    unsigned long long msk = __ballot(val == m);
    int amax = __ffsll(msk) - 1;   // first index achieving max (matches jnp.argmax)
    float e = (lane < V_) ? __expf(val - m) : 0.0f;
    float ssum = e;
#pragma unroll
    for (int off = 32; off > 0; off >>= 1) ssum += __shfl_xor(ssum, off);
    if (lane < V_) out[((size_t)b * T_ + tstep) * V_ + lane] = e / ssum;
    if (lane == 0) pre[b] = amax;
  }
}

extern "C" void kernel_launch(void* const* d_in, const int* in_sizes, int n_in,
                              void* d_out, int out_size, void* d_ws, size_t ws_size,
                              hipStream_t stream) {
  (void)in_sizes; (void)n_in; (void)out_size; (void)ws_size;
  const float* feat     = (const float*)d_in[0];
  const float* w_i2h    = (const float*)d_in[1];
  const float* w_h2h    = (const float*)d_in[2];
  const float* b_h2h    = (const float*)d_in[3];
  const float* w_score  = (const float*)d_in[4];
  const float* w_gru_ih = (const float*)d_in[5];
  const float* w_gru_hh = (const float*)d_in[6];
  const float* b_gru_ih = (const float*)d_in[7];
  const float* b_gru_hh = (const float*)d_in[8];
  const float* w_s1     = (const float*)d_in[9];
  const float* b_s1     = (const float*)d_in[10];
  const float* w_s2     = (const float*)d_in[11];
  const float* b_s2     = (const float*)d_in[12];
  float* out = (float*)d_out;

  char* ws = (char*)d_ws;
  size_t off = 0;
  auto alloc = [&](size_t bytes) { void* p = ws + off; off += (bytes + 255) & ~(size_t)255; return p; };
  float* fp       = (float*)alloc((size_t)B_ * N_ * H_ * 4);   // 33.55 MB
  float* part_ctx = (float*)alloc((size_t)B_ * 32 * C_ * 4);   // 2 MB
  float* part_l   = (float*)alloc((size_t)B_ * 32 * 4);
  float* h        = (float*)alloc((size_t)B_ * H_ * 4);
  float* pp       = (float*)alloc((size_t)B_ * H_ * 4);
  int*   pre      = (int*)alloc((size_t)B_ * 4);
  int*   cnt      = (int*)alloc((size_t)T_ * B_ * 4);

  init_kernel<<<64, 256, 0, stream>>>(b_h2h, h, pp, pre, cnt);
  fp_gemm<<<dim3((B_ * N_) / 64, H_ / 64), 256, 0, stream>>>(feat, w_i2h, fp);
  for (int tstep = 0; tstep < T_; ++tstep) {
    step_kernel<<<B_ * 32, 256, 0, stream>>>(
        tstep, feat, fp, w_score, w_gru_ih, w_gru_hh, b_gru_ih, b_gru_hh,
        w_s1, b_s1, w_s2, b_s2, w_h2h, b_h2h,
        h, pp, pre, part_ctx, part_l, cnt, out);
  }
}

// Round 2
// 146554.163 us; speedup vs baseline: 1.2774x; 1.2774x over previous
//
#include <hip/hip_runtime.h>
#include <math.h>

#define B_ 32
#define N_ 1024
#define C_ 512
#define H_ 256
#define V_ 50
#define T_ 501
#define CV_ 562     // C + V
#define G3_ 768     // 3*H
#define CHUNKS_ 64  // K1 blocks per batch row
#define POSB_ 16    // positions per K1 block

__device__ __forceinline__ float fast_rcp(float x) { return __builtin_amdgcn_rcpf(x); }
__device__ __forceinline__ float fast_tanh(float x) {
  float e = __expf(2.0f * x);
  return 1.0f - 2.0f * fast_rcp(e + 1.0f);
}
__device__ __forceinline__ float fast_sigmoid(float x) {
  return fast_rcp(1.0f + __expf(-x));
}

// ---------------- feat_proj GEMM: FP[m][h] = sum_c A[m][c] * W[h][c] (one-time) ----------------
__global__ __launch_bounds__(256) void fp_gemm(const float* __restrict__ A,
                                               const float* __restrict__ W,
                                               float* __restrict__ FP) {
  __shared__ __align__(16) float As[16][68];
  __shared__ __align__(16) float Ws[16][68];
  const int t = threadIdx.x;
  const int m0 = blockIdx.x * 64;
  const int h0 = blockIdx.y * 64;
  const int lr = t & 63;
  const int kg = t >> 6;
  const int tx = t & 15, ty = t >> 4;
  float acc[4][4] = {};
  for (int k0 = 0; k0 < C_; k0 += 16) {
    float4 av = *(const float4*)&A[(size_t)(m0 + lr) * C_ + k0 + kg * 4];
    float4 wv = *(const float4*)&W[(size_t)(h0 + lr) * C_ + k0 + kg * 4];
    As[kg*4+0][lr] = av.x; As[kg*4+1][lr] = av.y; As[kg*4+2][lr] = av.z; As[kg*4+3][lr] = av.w;
    Ws[kg*4+0][lr] = wv.x; Ws[kg*4+1][lr] = wv.y; Ws[kg*4+2][lr] = wv.z; Ws[kg*4+3][lr] = wv.w;
    __syncthreads();
#pragma unroll
    for (int kk = 0; kk < 16; ++kk) {
      float4 a = *(const float4*)&As[kk][ty * 4];
      float4 w = *(const float4*)&Ws[kk][tx * 4];
      acc[0][0] += a.x*w.x; acc[0][1] += a.x*w.y; acc[0][2] += a.x*w.z; acc[0][3] += a.x*w.w;
      acc[1][0] += a.y*w.x; acc[1][1] += a.y*w.y; acc[1][2] += a.y*w.z; acc[1][3] += a.y*w.w;
      acc[2][0] += a.z*w.x; acc[2][1] += a.z*w.y; acc[2][2] += a.z*w.z; acc[2][3] += a.z*w.w;
      acc[3][0] += a.w*w.x; acc[3][1] += a.w*w.y; acc[3][2] += a.w*w.z; acc[3][3] += a.w*w.w;
    }
    __syncthreads();
  }
#pragma unroll
  for (int i = 0; i < 4; ++i) {
    float4 o; o.x = acc[i][0]; o.y = acc[i][1]; o.z = acc[i][2]; o.w = acc[i][3];
    *(float4*)&FP[(size_t)(m0 + ty*4 + i) * H_ + h0 + tx*4] = o;
  }
}

// ---------------- weight transpose (one-time): dstA[c][j] = src[j][c] for c<splitc, rest -> dstB ----------------
__global__ void transpose_split(const float* __restrict__ src, float* __restrict__ dstA,
                                float* __restrict__ dstB, int rows, int cols, int splitc) {
  int i = blockIdx.x * 256 + threadIdx.x;
  if (i >= rows * cols) return;
  int j = i / cols, c = i - j * cols;
  float v = src[i];
  if (c < splitc) dstA[(size_t)c * rows + j] = v;
  else            dstB[(size_t)(c - splitc) * rows + j] = v;
}

// ---------------- init ----------------
__global__ void init_kernel(const float* __restrict__ b_h2h, float* __restrict__ h,
                            float* __restrict__ pp, int* __restrict__ pre,
                            int* __restrict__ cnt) {
  int i = blockIdx.x * blockDim.x + threadIdx.x;
  if (i < B_ * H_) { h[i] = 0.0f; pp[i] = b_h2h[i & (H_ - 1)]; }
  if (i < B_) pre[i] = 0;
  if (i < T_ * B_) cnt[i] = 0;
}

// ---------------- K1: attention scores -> exp -> partial ctx; ticketed combine -> ctx_full ----------------
// grid = B*CHUNKS blocks, block = 256 (4 waves, 4 positions each)
__global__ __launch_bounds__(256) void k1_attn(
    int tstep,
    const float* __restrict__ feat, const float* __restrict__ fp,
    const float* __restrict__ w_score, const float* __restrict__ pp,
    float* __restrict__ part_ctx, float* __restrict__ part_l,
    int* __restrict__ cnt, float* __restrict__ ctx_full) {
  __shared__ __align__(16) float lds_ctx[4 * C_];
  __shared__ float lds_l[4];
  __shared__ int sflag;

  const int t = threadIdx.x;
  const int wv = t >> 6;
  const int lane = t & 63;
  const int b = blockIdx.x >> 6;        // / CHUNKS_
  const int chunk = blockIdx.x & (CHUNKS_ - 1);

  float4 ppr = *(const float4*)&pp[b * H_ + lane * 4];
  float4 wsr = *(const float4*)&w_score[lane * 4];
  float aA0 = 0.f, aA1 = 0.f, aA2 = 0.f, aA3 = 0.f;
  float aB0 = 0.f, aB1 = 0.f, aB2 = 0.f, aB3 = 0.f;
  float lacc = 0.f;
  const float* fpb = fp + (size_t)b * N_ * H_;
  const float* fb  = feat + (size_t)b * N_ * C_;
  const int n0 = chunk * POSB_ + wv * 4;
#pragma unroll
  for (int i = 0; i < 4; ++i) {
    const int n = n0 + i;
    float4 v = *(const float4*)&fpb[(size_t)n * H_ + lane * 4];
    float s = fast_tanh(v.x + ppr.x) * wsr.x + fast_tanh(v.y + ppr.y) * wsr.y
            + fast_tanh(v.z + ppr.z) * wsr.z + fast_tanh(v.w + ppr.w) * wsr.w;
#pragma unroll
    for (int off = 32; off > 0; off >>= 1) s += __shfl_xor(s, off);
    float p = __expf(s);   // |s| <= sum|w_score| ~ 10 -> safe without max-subtraction
    lacc += p;
    const float* frow = &fb[(size_t)n * C_ + lane * 8];
    float4 fa = *(const float4*)frow;
    float4 fc = *(const float4*)(frow + 4);
    aA0 += p * fa.x; aA1 += p * fa.y; aA2 += p * fa.z; aA3 += p * fa.w;
    aB0 += p * fc.x; aB1 += p * fc.y; aB2 += p * fc.z; aB3 += p * fc.w;
  }
  {
    float4 o0; o0.x = aA0; o0.y = aA1; o0.z = aA2; o0.w = aA3;
    float4 o1; o1.x = aB0; o1.y = aB1; o1.z = aB2; o1.w = aB3;
    *(float4*)&lds_ctx[wv * C_ + lane * 8] = o0;
    *(float4*)&lds_ctx[wv * C_ + lane * 8 + 4] = o1;
  }
  if (lane == 0) lds_l[wv] = lacc;
  __syncthreads();
  {
    float c0 = lds_ctx[t] + lds_ctx[C_ + t] + lds_ctx[2 * C_ + t] + lds_ctx[3 * C_ + t];
    float c1 = lds_ctx[t + 256] + lds_ctx[C_ + t + 256] + lds_ctx[2 * C_ + t + 256] + lds_ctx[3 * C_ + t + 256];
    float* pc = &part_ctx[((size_t)b * CHUNKS_ + chunk) * C_];
    pc[t] = c0;
    pc[t + 256] = c1;
    if (t == 0) part_l[b * CHUNKS_ + chunk] = lds_l[0] + lds_l[1] + lds_l[2] + lds_l[3];
  }
  __threadfence();
  __syncthreads();
  if (t == 0) sflag = atomicAdd(&cnt[tstep * B_ + b], 1);
  __syncthreads();
  if (sflag != CHUNKS_ - 1) return;   // last-arriving block per b does the (cheap) combine
  __threadfence();

  float lt = 0.f;
#pragma unroll 8
  for (int k = 0; k < CHUNKS_; ++k) lt += part_l[b * CHUNKS_ + k];
  const float invl = 1.0f / lt;
  float d0 = 0.f, d1 = 0.f;
#pragma unroll 8
  for (int k = 0; k < CHUNKS_; ++k) {
    const float* q = &part_ctx[((size_t)b * CHUNKS_ + k) * C_];
    d0 += q[t];
    d1 += q[t + 256];
  }
  ctx_full[b * C_ + t] = d0 * invl;
  ctx_full[b * C_ + t + 256] = d1 * invl;
}

// ---------------- K2: gi = Wih @ ctx, gh = Whh @ h (transposed weights, c-split, b-grouped) ----------------
// grid = dim3(4 c-splits, 6 j-tiles, 8 b-groups), block = 128
__global__ __launch_bounds__(128) void k2_gemv(
    const float* __restrict__ ctx_full, const float* __restrict__ h,
    const float* __restrict__ WtA, const float* __restrict__ WtH,
    float* __restrict__ part_gi, float* __restrict__ part_gh) {
  __shared__ float xs[4][128];
  __shared__ float hs[4][64];
  const int cs = blockIdx.x, jg = blockIdx.y, bg = blockIdx.z;
  const int t = threadIdx.x;
#pragma unroll
  for (int q = 0; q < 4; ++q) {
    int idx = q * 128 + t; int bi = idx >> 7, cc = idx & 127;
    xs[bi][cc] = ctx_full[(bg * 4 + bi) * C_ + cs * 128 + cc];
  }
#pragma unroll
  for (int q = 0; q < 2; ++q) {
    int idx = q * 128 + t; int bi = idx >> 6, cc = idx & 63;
    hs[bi][cc] = h[(bg * 4 + bi) * H_ + cs * 64 + cc];
  }
  __syncthreads();
  float ai0 = 0.f, ai1 = 0.f, ai2 = 0.f, ai3 = 0.f;
  const float* wa = WtA + (size_t)(cs * 128) * G3_ + jg * 128 + t;
#pragma unroll 8
  for (int cc = 0; cc < 128; ++cc) {
    float w = wa[(size_t)cc * G3_];
    ai0 += w * xs[0][cc]; ai1 += w * xs[1][cc]; ai2 += w * xs[2][cc]; ai3 += w * xs[3][cc];
  }
  float ah0 = 0.f, ah1 = 0.f, ah2 = 0.f, ah3 = 0.f;
  const float* wh = WtH + (size_t)(cs * 64) * G3_ + jg * 128 + t;
#pragma unroll 8
  for (int cc = 0; cc < 64; ++cc) {
    float w = wh[(size_t)cc * G3_];
    ah0 += w * hs[0][cc]; ah1 += w * hs[1][cc]; ah2 += w * hs[2][cc]; ah3 += w * hs[3][cc];
  }
  const int j = jg * 128 + t;
  part_gi[((size_t)cs * B_ + bg * 4 + 0) * G3_ + j] = ai0;
  part_gi[((size_t)cs * B_ + bg * 4 + 1) * G3_ + j] = ai1;
  part_gi[((size_t)cs * B_ + bg * 4 + 2) * G3_ + j] = ai2;
  part_gi[((size_t)cs * B_ + bg * 4 + 3) * G3_ + j] = ai3;
  part_gh[((size_t)cs * B_ + bg * 4 + 0) * G3_ + j] = ah0;
  part_gh[((size_t)cs * B_ + bg * 4 + 1) * G3_ + j] = ah1;
  part_gh[((size_t)cs * B_ + bg * 4 + 2) * G3_ + j] = ah2;
  part_gh[((size_t)cs * B_ + bg * 4 + 3) * G3_ + j] = ah3;
}

// ---------------- K3: gates combine -> GRU -> s1 || pp -> struct -> argmax -> out ----------------
// grid = 32 (one per b), block = 512
__global__ __launch_bounds__(512) void k3_tail(
    int tstep,
    const float* __restrict__ part_gi, const float* __restrict__ part_gh,
    const float* __restrict__ b_gru_ih, const float* __restrict__ b_gru_hh,
    const float* __restrict__ WtO,
    const float* __restrict__ Wt_s1, const float* __restrict__ b_s1,
    const float* __restrict__ Wt_h2h, const float* __restrict__ b_h2h,
    const float* __restrict__ w_s2, const float* __restrict__ b_s2,
    float* __restrict__ h, float* __restrict__ pp, int* __restrict__ pre,
    float* __restrict__ out) {
  __shared__ __align__(16) float shn[H_];
  __shared__ __align__(16) float ss1[H_];
  __shared__ float sst[64];
  const int b = blockIdx.x;
  const int t = threadIdx.x;
  const int prev = pre[b];

  if (t < 256) {
    const float* wo = WtO + (size_t)prev * G3_;
    float gi0 = b_gru_ih[t]       + wo[t];
    float gi1 = b_gru_ih[t + 256] + wo[t + 256];
    float gi2 = b_gru_ih[t + 512] + wo[t + 512];
    float gh0 = b_gru_hh[t], gh1 = b_gru_hh[t + 256], gh2 = b_gru_hh[t + 512];
#pragma unroll
    for (int cs = 0; cs < 4; ++cs) {
      const float* pg = part_gi + ((size_t)cs * B_ + b) * G3_;
      const float* ph = part_gh + ((size_t)cs * B_ + b) * G3_;
      gi0 += pg[t]; gi1 += pg[t + 256]; gi2 += pg[t + 512];
      gh0 += ph[t]; gh1 += ph[t + 256]; gh2 += ph[t + 512];
    }
    const float h_old = h[b * H_ + t];
    const float r = fast_sigmoid(gi0 + gh0);
    const float z = fast_sigmoid(gi1 + gh1);
    const float nn = fast_tanh(gi2 + r * gh2);
    const float hnew = (1.0f - z) * nn + z * h_old;
    h[b * H_ + t] = hnew;
    shn[t] = hnew;
  }
  __syncthreads();

  if (t < 256) {
    float acc = b_s1[t];
#pragma unroll 8
    for (int c = 0; c < H_; ++c) acc += Wt_s1[(size_t)c * H_ + t] * shn[c];
    ss1[t] = acc;
  } else {
    const int tt = t - 256;
    float acc = b_h2h[tt];
#pragma unroll 8
    for (int c = 0; c < H_; ++c) acc += Wt_h2h[(size_t)c * H_ + tt] * shn[c];
    pp[b * H_ + tt] = acc;
  }
  __syncthreads();

  const int wv = t >> 6, lane = t & 63;
  for (int v = wv; v < V_; v += 8) {
    float4 wr = *(const float4*)&w_s2[(size_t)v * H_ + lane * 4];
    float4 sv = *(const float4*)&ss1[lane * 4];
    float acc = wr.x * sv.x + wr.y * sv.y + wr.z * sv.z + wr.w * sv.w;
#pragma unroll
    for (int off = 32; off > 0; off >>= 1) acc += __shfl_xor(acc, off);
    if (lane == 0) sst[v] = acc + b_s2[v];
  }
  __syncthreads();

  if (t < 64) {
    float val = (lane < V_) ? sst[lane] : -INFINITY;
    float m = val;
#pragma unroll
    for (int off = 32; off > 0; off >>= 1) m = fmaxf(m, __shfl_xor(m, off));
    unsigned long long msk = __ballot(val == m);
    int amax = __ffsll(msk) - 1;
    float e = (lane < V_) ? __expf(val - m) : 0.0f;
    float ssum = e;
#pragma unroll
    for (int off = 32; off > 0; off >>= 1) ssum += __shfl_xor(ssum, off);
    if (lane < V_) out[((size_t)b * T_ + tstep) * V_ + lane] = e / ssum;
    if (lane == 0) pre[b] = amax;
  }
}

extern "C" void kernel_launch(void* const* d_in, const int* in_sizes, int n_in,
                              void* d_out, int out_size, void* d_ws, size_t ws_size,
                              hipStream_t stream) {
  (void)in_sizes; (void)n_in; (void)out_size; (void)ws_size;
  const float* feat     = (const float*)d_in[0];
  const float* w_i2h    = (const float*)d_in[1];
  const float* w_h2h    = (const float*)d_in[2];
  const float* b_h2h    = (const float*)d_in[3];
  const float* w_score  = (const float*)d_in[4];
  const float* w_gru_ih = (const float*)d_in[5];
  const float* w_gru_hh = (const float*)d_in[6];
  const float* b_gru_ih = (const float*)d_in[7];
  const float* b_gru_hh = (const float*)d_in[8];
  const float* w_s1     = (const float*)d_in[9];
  const float* b_s1     = (const float*)d_in[10];
  const float* w_s2     = (const float*)d_in[11];
  const float* b_s2     = (const float*)d_in[12];
  float* out = (float*)d_out;

  char* ws = (char*)d_ws;
  size_t off = 0;
  auto alloc = [&](size_t bytes) { void* p = ws + off; off += (bytes + 255) & ~(size_t)255; return p; };
  float* fp       = (float*)alloc((size_t)B_ * N_ * H_ * 4);        // 33.55 MB
  float* part_ctx = (float*)alloc((size_t)B_ * CHUNKS_ * C_ * 4);   // 4.19 MB
  float* part_l   = (float*)alloc((size_t)B_ * CHUNKS_ * 4);
  float* ctx_full = (float*)alloc((size_t)B_ * C_ * 4);
  float* part_gi  = (float*)alloc((size_t)4 * B_ * G3_ * 4);        // 393 KB
  float* part_gh  = (float*)alloc((size_t)4 * B_ * G3_ * 4);
  float* WtA      = (float*)alloc((size_t)C_ * G3_ * 4);            // 1.57 MB
  float* WtO      = (float*)alloc((size_t)V_ * G3_ * 4);
  float* WtH      = (float*)alloc((size_t)H_ * G3_ * 4);            // 786 KB
  float* Wt_s1    = (float*)alloc((size_t)H_ * H_ * 4);
  float* Wt_h2h   = (float*)alloc((size_t)H_ * H_ * 4);
  float* h        = (float*)alloc((size_t)B_ * H_ * 4);
  float* pp       = (float*)alloc((size_t)B_ * H_ * 4);
  int*   pre      = (int*)alloc((size_t)B_ * 4);
  int*   cnt      = (int*)alloc((size_t)T_ * B_ * 4);

  init_kernel<<<64, 256, 0, stream>>>(b_h2h, h, pp, pre, cnt);
  fp_gemm<<<dim3((B_ * N_) / 64, H_ / 64), 256, 0, stream>>>(feat, w_i2h, fp);
  transpose_split<<<(G3_ * CV_ + 255) / 256, 256, 0, stream>>>(w_gru_ih, WtA, WtO, G3_, CV_, C_);
  transpose_split<<<(G3_ * H_ + 255) / 256, 256, 0, stream>>>(w_gru_hh, WtH, WtH, G3_, H_, H_);
  transpose_split<<<(H_ * H_ + 255) / 256, 256, 0, stream>>>(w_s1, Wt_s1, Wt_s1, H_, H_, H_);
  transpose_split<<<(H_ * H_ + 255) / 256, 256, 0, stream>>>(w_h2h, Wt_h2h, Wt_h2h, H_, H_, H_);

  for (int tstep = 0; tstep < T_; ++tstep) {
    k1_attn<<<B_ * CHUNKS_, 256, 0, stream>>>(tstep, feat, fp, w_score, pp,
                                              part_ctx, part_l, cnt, ctx_full);
    k2_gemv<<<dim3(4, 6, 8), 128, 0, stream>>>(ctx_full, h, WtA, WtH, part_gi, part_gh);
    k3_tail<<<B_, 512, 0, stream>>>(tstep, part_gi, part_gh, b_gru_ih, b_gru_hh, WtO,
                                    Wt_s1, b_s1, Wt_h2h, b_h2h, w_s2, b_s2,
                                    h, pp, pre, out);
  }
}

// Round 3
// 36318.033 us; speedup vs baseline: 5.1549x; 4.0353x over previous
//
#include <hip/hip_runtime.h>
#include <math.h>

#define B_ 32
#define N_ 1024
#define C_ 512
#define H_ 256
#define V_ 50
#define T_ 501
#define CV_ 562     // C + V
#define G3_ 768     // 3*H
#define CHUNKS_ 32  // K1 blocks per batch row
#define POSB_ 32    // positions per K1 block

__device__ __forceinline__ float fast_rcp(float x) { return __builtin_amdgcn_rcpf(x); }
__device__ __forceinline__ float fast_tanh(float x) {
  float e = __expf(2.0f * x);
  return 1.0f - 2.0f * fast_rcp(e + 1.0f);
}
__device__ __forceinline__ float fast_sigmoid(float x) {
  return fast_rcp(1.0f + __expf(-x));
}

// ---------------- feat_proj GEMM: FP[m][h] = sum_c A[m][c] * W[h][c] (one-time) ----------------
__global__ __launch_bounds__(256) void fp_gemm(const float* __restrict__ A,
                                               const float* __restrict__ W,
                                               float* __restrict__ FP) {
  __shared__ __align__(16) float As[16][68];
  __shared__ __align__(16) float Ws[16][68];
  const int t = threadIdx.x;
  const int m0 = blockIdx.x * 64;
  const int h0 = blockIdx.y * 64;
  const int lr = t & 63;
  const int kg = t >> 6;
  const int tx = t & 15, ty = t >> 4;
  float acc[4][4] = {};
  for (int k0 = 0; k0 < C_; k0 += 16) {
    float4 av = *(const float4*)&A[(size_t)(m0 + lr) * C_ + k0 + kg * 4];
    float4 wv = *(const float4*)&W[(size_t)(h0 + lr) * C_ + k0 + kg * 4];
    As[kg*4+0][lr] = av.x; As[kg*4+1][lr] = av.y; As[kg*4+2][lr] = av.z; As[kg*4+3][lr] = av.w;
    Ws[kg*4+0][lr] = wv.x; Ws[kg*4+1][lr] = wv.y; Ws[kg*4+2][lr] = wv.z; Ws[kg*4+3][lr] = wv.w;
    __syncthreads();
#pragma unroll
    for (int kk = 0; kk < 16; ++kk) {
      float4 a = *(const float4*)&As[kk][ty * 4];
      float4 w = *(const float4*)&Ws[kk][tx * 4];
      acc[0][0] += a.x*w.x; acc[0][1] += a.x*w.y; acc[0][2] += a.x*w.z; acc[0][3] += a.x*w.w;
      acc[1][0] += a.y*w.x; acc[1][1] += a.y*w.y; acc[1][2] += a.y*w.z; acc[1][3] += a.y*w.w;
      acc[2][0] += a.z*w.x; acc[2][1] += a.z*w.y; acc[2][2] += a.z*w.z; acc[2][3] += a.z*w.w;
      acc[3][0] += a.w*w.x; acc[3][1] += a.w*w.y; acc[3][2] += a.w*w.z; acc[3][3] += a.w*w.w;
    }
    __syncthreads();
  }
#pragma unroll
  for (int i = 0; i < 4; ++i) {
    float4 o; o.x = acc[i][0]; o.y = acc[i][1]; o.z = acc[i][2]; o.w = acc[i][3];
    *(float4*)&FP[(size_t)(m0 + ty*4 + i) * H_ + h0 + tx*4] = o;
  }
}

// ---------------- weight transpose (one-time): dstA[c][j] = src[j][c] for c<splitc, rest -> dstB ----------------
__global__ void transpose_split(const float* __restrict__ src, float* __restrict__ dstA,
                                float* __restrict__ dstB, int rows, int cols, int splitc) {
  int i = blockIdx.x * 256 + threadIdx.x;
  if (i >= rows * cols) return;
  int j = i / cols, c = i - j * cols;
  float v = src[i];
  if (c < splitc) dstA[(size_t)c * rows + j] = v;
  else            dstB[(size_t)(c - splitc) * rows + j] = v;
}

// ---------------- init: h=0, pp=b_h2h, pre=0, ctx_raw=0, l_total=0 ----------------
__global__ void init_kernel(const float* __restrict__ b_h2h, float* __restrict__ h,
                            float* __restrict__ pp, int* __restrict__ pre,
                            float* __restrict__ ctx_raw, float* __restrict__ l_total) {
  int i = blockIdx.x * blockDim.x + threadIdx.x;
  if (i < B_ * H_) { h[i] = 0.0f; pp[i] = b_h2h[i & (H_ - 1)]; }
  if (i < B_ * C_) ctx_raw[i] = 0.0f;
  if (i < B_) { pre[i] = 0; l_total[i] = 0.0f; }
}

// ---------------- K1: attention scores -> exp -> partial ctx -> atomic accumulate ----------------
// grid = B*CHUNKS blocks, block = 256 (4 waves, 8 positions each). NO fences, NO tickets.
__global__ __launch_bounds__(256) void k1_attn(
    const float* __restrict__ feat, const float* __restrict__ fp,
    const float* __restrict__ w_score, const float* __restrict__ pp,
    float* __restrict__ ctx_raw, float* __restrict__ l_total) {
  __shared__ __align__(16) float lds_ctx[4 * C_];
  __shared__ float lds_l[4];

  const int t = threadIdx.x;
  const int wv = t >> 6;
  const int lane = t & 63;
  const int b = blockIdx.x >> 5;        // / CHUNKS_
  const int chunk = blockIdx.x & (CHUNKS_ - 1);

  float4 ppr = *(const float4*)&pp[b * H_ + lane * 4];
  float4 wsr = *(const float4*)&w_score[lane * 4];
  float aA0 = 0.f, aA1 = 0.f, aA2 = 0.f, aA3 = 0.f;
  float aB0 = 0.f, aB1 = 0.f, aB2 = 0.f, aB3 = 0.f;
  float lacc = 0.f;
  const float* fpb = fp + (size_t)b * N_ * H_;
  const float* fb  = feat + (size_t)b * N_ * C_;
  const int n0 = chunk * POSB_ + wv * 8;
#pragma unroll 2
  for (int i = 0; i < 8; ++i) {
    const int n = n0 + i;
    float4 v = *(const float4*)&fpb[(size_t)n * H_ + lane * 4];
    float s = fast_tanh(v.x + ppr.x) * wsr.x + fast_tanh(v.y + ppr.y) * wsr.y
            + fast_tanh(v.z + ppr.z) * wsr.z + fast_tanh(v.w + ppr.w) * wsr.w;
#pragma unroll
    for (int off = 32; off > 0; off >>= 1) s += __shfl_xor(s, off);
    float p = __expf(s);   // |s| <= sum|w_score| ~ 10 -> safe without max-subtraction
    lacc += p;
    const float* frow = &fb[(size_t)n * C_ + lane * 8];
    float4 fa = *(const float4*)frow;
    float4 fc = *(const float4*)(frow + 4);
    aA0 += p * fa.x; aA1 += p * fa.y; aA2 += p * fa.z; aA3 += p * fa.w;
    aB0 += p * fc.x; aB1 += p * fc.y; aB2 += p * fc.z; aB3 += p * fc.w;
  }
  {
    float4 o0; o0.x = aA0; o0.y = aA1; o0.z = aA2; o0.w = aA3;
    float4 o1; o1.x = aB0; o1.y = aB1; o1.z = aB2; o1.w = aB3;
    *(float4*)&lds_ctx[wv * C_ + lane * 8] = o0;
    *(float4*)&lds_ctx[wv * C_ + lane * 8 + 4] = o1;
  }
  if (lane == 0) lds_l[wv] = lacc;
  __syncthreads();
  {
    float c0 = lds_ctx[t] + lds_ctx[C_ + t] + lds_ctx[2 * C_ + t] + lds_ctx[3 * C_ + t];
    float c1 = lds_ctx[t + 256] + lds_ctx[C_ + t + 256] + lds_ctx[2 * C_ + t + 256] + lds_ctx[3 * C_ + t + 256];
    unsafeAtomicAdd(&ctx_raw[b * C_ + t], c0);
    unsafeAtomicAdd(&ctx_raw[b * C_ + t + 256], c1);
    if (t == 0) unsafeAtomicAdd(&l_total[b], lds_l[0] + lds_l[1] + lds_l[2] + lds_l[3]);
  }
}

// ---------------- K2: full per-b tail. grid = 32, block = 768 (12 waves) ----------------
__global__ __launch_bounds__(768) void k2_tail(
    int tstep,
    const float* __restrict__ ctx_raw_c, float* __restrict__ ctx_raw,
    const float* __restrict__ l_total_c, float* __restrict__ l_total,
    const float* __restrict__ WtA, const float* __restrict__ WtO, const float* __restrict__ WtH,
    const float* __restrict__ b_gru_ih, const float* __restrict__ b_gru_hh,
    const float* __restrict__ Wt_s1, const float* __restrict__ b_s1,
    const float* __restrict__ Wt_h2h, const float* __restrict__ b_h2h,
    const float* __restrict__ w_s2, const float* __restrict__ b_s2,
    float* __restrict__ h, float* __restrict__ pp, int* __restrict__ pre,
    float* __restrict__ out) {
  __shared__ __align__(16) float sctx[C_];
  __shared__ __align__(16) float sh[H_];
  __shared__ __align__(16) float sgi[G3_];
  __shared__ __align__(16) float sgh[G3_];
  __shared__ __align__(16) float shn[H_];
  __shared__ __align__(16) float ss1[H_];
  __shared__ float sst[64];
  const int b = blockIdx.x;
  const int t = threadIdx.x;
  const int prev = pre[b];

  const float invl = 1.0f / l_total_c[b];
  if (t < C_) {
    sctx[t] = ctx_raw_c[b * C_ + t] * invl;
    ctx_raw[b * C_ + t] = 0.0f;          // reset accumulator for next step
  } else if (t < C_ + H_) {
    sh[t - C_] = h[b * H_ + (t - C_)];
  }
  __syncthreads();
  if (t == 0) l_total[b] = 0.0f;         // all threads consumed invl already

  // gi = WtA^T-style coalesced GEMV over c=512 ; gh over c=256 (j = t, 0..767)
  {
    float ai = 0.f;
    const float* wa = WtA + t;
#pragma unroll 8
    for (int c = 0; c < C_; ++c) ai += wa[(size_t)c * G3_] * sctx[c];
    float ah = 0.f;
    const float* wh = WtH + t;
#pragma unroll 8
    for (int c = 0; c < H_; ++c) ah += wh[(size_t)c * G3_] * sh[c];
    sgi[t] = ai + b_gru_ih[t] + WtO[(size_t)prev * G3_ + t];
    sgh[t] = ah + b_gru_hh[t];
  }
  __syncthreads();

  if (t < H_) {
    const float h_old = sh[t];
    const float r = fast_sigmoid(sgi[t] + sgh[t]);
    const float z = fast_sigmoid(sgi[t + 256] + sgh[t + 256]);
    const float nn = fast_tanh(sgi[t + 512] + r * sgh[t + 512]);
    const float hnew = (1.0f - z) * nn + z * h_old;
    h[b * H_ + t] = hnew;
    shn[t] = hnew;
  }
  __syncthreads();

  if (t < H_) {
    float acc = b_s1[t];
    const float* w1 = Wt_s1 + t;
#pragma unroll 8
    for (int c = 0; c < H_; ++c) acc += w1[(size_t)c * H_] * shn[c];
    ss1[t] = acc;
  } else if (t < 2 * H_) {
    const int tt = t - H_;
    float acc = b_h2h[tt];
    const float* wh2 = Wt_h2h + tt;
#pragma unroll 8
    for (int c = 0; c < H_; ++c) acc += wh2[(size_t)c * H_] * shn[c];
    pp[b * H_ + tt] = acc;
  }
  __syncthreads();

  const int wv = t >> 6, lane = t & 63;
  for (int v = wv; v < V_; v += 12) {
    float4 wr = *(const float4*)&w_s2[(size_t)v * H_ + lane * 4];
    float4 sv = *(const float4*)&ss1[lane * 4];
    float acc = wr.x * sv.x + wr.y * sv.y + wr.z * sv.z + wr.w * sv.w;
#pragma unroll
    for (int off = 32; off > 0; off >>= 1) acc += __shfl_xor(acc, off);
    if (lane == 0) sst[v] = acc + b_s2[v];
  }
  __syncthreads();

  if (t < 64) {
    float val = (lane < V_) ? sst[lane] : -INFINITY;
    float m = val;
#pragma unroll
    for (int off = 32; off > 0; off >>= 1) m = fmaxf(m, __shfl_xor(m, off));
    unsigned long long msk = __ballot(val == m);
    int amax = __ffsll(msk) - 1;   // first index achieving max (matches jnp.argmax)
    float e = (lane < V_) ? __expf(val - m) : 0.0f;
    float ssum = e;
#pragma unroll
    for (int off = 32; off > 0; off >>= 1) ssum += __shfl_xor(ssum, off);
    if (lane < V_) out[((size_t)b * T_ + tstep) * V_ + lane] = e / ssum;
    if (lane == 0) pre[b] = amax;
  }
}

extern "C" void kernel_launch(void* const* d_in, const int* in_sizes, int n_in,
                              void* d_out, int out_size, void* d_ws, size_t ws_size,
                              hipStream_t stream) {
  (void)in_sizes; (void)n_in; (void)out_size; (void)ws_size;
  const float* feat     = (const float*)d_in[0];
  const float* w_i2h    = (const float*)d_in[1];
  const float* w_h2h    = (const float*)d_in[2];
  const float* b_h2h    = (const float*)d_in[3];
  const float* w_score  = (const float*)d_in[4];
  const float* w_gru_ih = (const float*)d_in[5];
  const float* w_gru_hh = (const float*)d_in[6];
  const float* b_gru_ih = (const float*)d_in[7];
  const float* b_gru_hh = (const float*)d_in[8];
  const float* w_s1     = (const float*)d_in[9];
  const float* b_s1     = (const float*)d_in[10];
  const float* w_s2     = (const float*)d_in[11];
  const float* b_s2     = (const float*)d_in[12];
  float* out = (float*)d_out;

  char* ws = (char*)d_ws;
  size_t off = 0;
  auto alloc = [&](size_t bytes) { void* p = ws + off; off += (bytes + 255) & ~(size_t)255; return p; };
  float* fp       = (float*)alloc((size_t)B_ * N_ * H_ * 4);        // 33.55 MB
  float* ctx_raw  = (float*)alloc((size_t)B_ * C_ * 4);             // 64 KB (atomic accumulators)
  float* l_total  = (float*)alloc((size_t)B_ * 4);
  float* WtA      = (float*)alloc((size_t)C_ * G3_ * 4);            // 1.57 MB
  float* WtO      = (float*)alloc((size_t)V_ * G3_ * 4);
  float* WtH      = (float*)alloc((size_t)H_ * G3_ * 4);            // 786 KB
  float* Wt_s1    = (float*)alloc((size_t)H_ * H_ * 4);
  float* Wt_h2h   = (float*)alloc((size_t)H_ * H_ * 4);
  float* h        = (float*)alloc((size_t)B_ * H_ * 4);
  float* pp       = (float*)alloc((size_t)B_ * H_ * 4);
  int*   pre      = (int*)alloc((size_t)B_ * 4);

  init_kernel<<<64, 256, 0, stream>>>(b_h2h, h, pp, pre, ctx_raw, l_total);
  fp_gemm<<<dim3((B_ * N_) / 64, H_ / 64), 256, 0, stream>>>(feat, w_i2h, fp);
  transpose_split<<<(G3_ * CV_ + 255) / 256, 256, 0, stream>>>(w_gru_ih, WtA, WtO, G3_, CV_, C_);
  transpose_split<<<(G3_ * H_ + 255) / 256, 256, 0, stream>>>(w_gru_hh, WtH, WtH, G3_, H_, H_);
  transpose_split<<<(H_ * H_ + 255) / 256, 256, 0, stream>>>(w_s1, Wt_s1, Wt_s1, H_, H_, H_);
  transpose_split<<<(H_ * H_ + 255) / 256, 256, 0, stream>>>(w_h2h, Wt_h2h, Wt_h2h, H_, H_, H_);

  for (int tstep = 0; tstep < T_; ++tstep) {
    k1_attn<<<B_ * CHUNKS_, 256, 0, stream>>>(feat, fp, w_score, pp, ctx_raw, l_total);
    k2_tail<<<B_, 768, 0, stream>>>(tstep, ctx_raw, ctx_raw, l_total, l_total,
                                    WtA, WtO, WtH, b_gru_ih, b_gru_hh,
                                    Wt_s1, b_s1, Wt_h2h, b_h2h, w_s2, b_s2,
                                    h, pp, pre, out);
  }
}

// Round 6
// 20478.223 us; speedup vs baseline: 9.1421x; 1.7735x over previous
//
#include <hip/hip_runtime.h>
#include <math.h>

#define B_ 32
#define N_ 1024
#define C_ 512
#define H_ 256
#define V_ 50
#define T_ 501
#define CV_ 562     // C + V
#define G3_ 768     // 3*H
#define CHUNKS_ 32  // K1 blocks per batch row
#define POSB_ 32    // positions per K1 block

typedef float f32x4 __attribute__((ext_vector_type(4)));

__device__ __forceinline__ float fast_rcp(float x) { return __builtin_amdgcn_rcpf(x); }
__device__ __forceinline__ float fast_tanh(float x) {
  float e = __expf(2.0f * x);
  return 1.0f - 2.0f * fast_rcp(e + 1.0f);
}
__device__ __forceinline__ float fast_sigmoid(float x) {
  return fast_rcp(1.0f + __expf(-x));
}
__device__ __forceinline__ f32x4 ntload4(const float* p) {
  return __builtin_nontemporal_load((const f32x4*)p);
}

// ---------------- feat_proj GEMM: FP[m][h] = sum_c A[m][c] * W[h][c] (one-time) ----------------
__global__ __launch_bounds__(256) void fp_gemm(const float* __restrict__ A,
                                               const float* __restrict__ W,
                                               float* __restrict__ FP) {
  __shared__ __align__(16) float As[16][68];
  __shared__ __align__(16) float Ws[16][68];
  const int t = threadIdx.x;
  const int m0 = blockIdx.x * 64;
  const int h0 = blockIdx.y * 64;
  const int lr = t & 63;
  const int kg = t >> 6;
  const int tx = t & 15, ty = t >> 4;
  float acc[4][4] = {};
  for (int k0 = 0; k0 < C_; k0 += 16) {
    float4 av = *(const float4*)&A[(size_t)(m0 + lr) * C_ + k0 + kg * 4];
    float4 wv = *(const float4*)&W[(size_t)(h0 + lr) * C_ + k0 + kg * 4];
    As[kg*4+0][lr] = av.x; As[kg*4+1][lr] = av.y; As[kg*4+2][lr] = av.z; As[kg*4+3][lr] = av.w;
    Ws[kg*4+0][lr] = wv.x; Ws[kg*4+1][lr] = wv.y; Ws[kg*4+2][lr] = wv.z; Ws[kg*4+3][lr] = wv.w;
    __syncthreads();
#pragma unroll
    for (int kk = 0; kk < 16; ++kk) {
      float4 a = *(const float4*)&As[kk][ty * 4];
      float4 w = *(const float4*)&Ws[kk][tx * 4];
      acc[0][0] += a.x*w.x; acc[0][1] += a.x*w.y; acc[0][2] += a.x*w.z; acc[0][3] += a.x*w.w;
      acc[1][0] += a.y*w.x; acc[1][1] += a.y*w.y; acc[1][2] += a.y*w.z; acc[1][3] += a.y*w.w;
      acc[2][0] += a.z*w.x; acc[2][1] += a.z*w.y; acc[2][2] += a.z*w.z; acc[2][3] += a.z*w.w;
      acc[3][0] += a.w*w.x; acc[3][1] += a.w*w.y; acc[3][2] += a.w*w.z; acc[3][3] += a.w*w.w;
    }
    __syncthreads();
  }
#pragma unroll
  for (int i = 0; i < 4; ++i) {
    float4 o; o.x = acc[i][0]; o.y = acc[i][1]; o.z = acc[i][2]; o.w = acc[i][3];
    *(float4*)&FP[(size_t)(m0 + ty*4 + i) * H_ + h0 + tx*4] = o;
  }
}

// ---------------- weight transpose (one-time): dstA[c][j] = src[j][c] for c<splitc, rest -> dstB ----------------
__global__ void transpose_split(const float* __restrict__ src, float* __restrict__ dstA,
                                float* __restrict__ dstB, int rows, int cols, int splitc) {
  int i = blockIdx.x * 256 + threadIdx.x;
  if (i >= rows * cols) return;
  int j = i / cols, c = i - j * cols;
  float v = src[i];
  if (c < splitc) dstA[(size_t)c * rows + j] = v;
  else            dstB[(size_t)(c - splitc) * rows + j] = v;
}

// ---------------- init: h=0, pp=b_h2h, pre=0, ctx_raw=0, l_total=0 ----------------
__global__ void init_kernel(const float* __restrict__ b_h2h, float* __restrict__ h,
                            float* __restrict__ pp, int* __restrict__ pre,
                            float* __restrict__ ctx_raw, float* __restrict__ l_total) {
  int i = blockIdx.x * blockDim.x + threadIdx.x;
  if (i < B_ * H_) { h[i] = 0.0f; pp[i] = b_h2h[i & (H_ - 1)]; }
  if (i < B_ * C_) ctx_raw[i] = 0.0f;
  if (i < B_) { pre[i] = 0; l_total[i] = 0.0f; }
}

// ---------------- K1: attention scores -> exp -> partial ctx -> atomic accumulate ----------------
// grid = B*CHUNKS blocks, block = 256 (4 waves, 8 positions each). nt loads keep L2 clean.
__global__ __launch_bounds__(256) void k1_attn(
    const float* __restrict__ feat, const float* __restrict__ fp,
    const float* __restrict__ w_score, const float* __restrict__ pp,
    float* __restrict__ ctx_raw, float* __restrict__ l_total) {
  __shared__ __align__(16) float lds_ctx[4 * C_];
  __shared__ float lds_l[4];

  const int t = threadIdx.x;
  const int wv = t >> 6;
  const int lane = t & 63;
  const int b = blockIdx.x >> 5;        // / CHUNKS_
  const int chunk = blockIdx.x & (CHUNKS_ - 1);

  float4 ppr = *(const float4*)&pp[b * H_ + lane * 4];
  float4 wsr = *(const float4*)&w_score[lane * 4];
  float aA0 = 0.f, aA1 = 0.f, aA2 = 0.f, aA3 = 0.f;
  float aB0 = 0.f, aB1 = 0.f, aB2 = 0.f, aB3 = 0.f;
  float lacc = 0.f;
  const float* fpb = fp + (size_t)b * N_ * H_;
  const float* fb  = feat + (size_t)b * N_ * C_;
  const int n0 = chunk * POSB_ + wv * 8;
#pragma unroll 2
  for (int i = 0; i < 8; ++i) {
    const int n = n0 + i;
    f32x4 v = ntload4(&fpb[(size_t)n * H_ + lane * 4]);
    float s = fast_tanh(v.x + ppr.x) * wsr.x + fast_tanh(v.y + ppr.y) * wsr.y
            + fast_tanh(v.z + ppr.z) * wsr.z + fast_tanh(v.w + ppr.w) * wsr.w;
#pragma unroll
    for (int off = 32; off > 0; off >>= 1) s += __shfl_xor(s, off);
    float p = __expf(s);   // |s| <= sum|w_score| ~ 10 -> safe without max-subtraction
    lacc += p;
    const float* frow = &fb[(size_t)n * C_ + lane * 8];
    f32x4 fa = ntload4(frow);
    f32x4 fc = ntload4(frow + 4);
    aA0 += p * fa.x; aA1 += p * fa.y; aA2 += p * fa.z; aA3 += p * fa.w;
    aB0 += p * fc.x; aB1 += p * fc.y; aB2 += p * fc.z; aB3 += p * fc.w;
  }
  {
    float4 o0; o0.x = aA0; o0.y = aA1; o0.z = aA2; o0.w = aA3;
    float4 o1; o1.x = aB0; o1.y = aB1; o1.z = aB2; o1.w = aB3;
    *(float4*)&lds_ctx[wv * C_ + lane * 8] = o0;
    *(float4*)&lds_ctx[wv * C_ + lane * 8 + 4] = o1;
  }
  if (lane == 0) lds_l[wv] = lacc;
  __syncthreads();
  {
    float c0 = lds_ctx[t] + lds_ctx[C_ + t] + lds_ctx[2 * C_ + t] + lds_ctx[3 * C_ + t];
    float c1 = lds_ctx[t + 256] + lds_ctx[C_ + t + 256] + lds_ctx[2 * C_ + t + 256] + lds_ctx[3 * C_ + t + 256];
    unsafeAtomicAdd(&ctx_raw[b * C_ + t], c0);
    unsafeAtomicAdd(&ctx_raw[b * C_ + t + 256], c1);
    if (t == 0) unsafeAtomicAdd(&l_total[b], lds_l[0] + lds_l[1] + lds_l[2] + lds_l[3]);
  }
}

// ---------------- K2a: gate GEMM (weights read ONCE per step) ----------------
// pgi[ks][b][j] = sum_{c in ks-split} WtA[c][j]*ctx_raw[b][c]   (K=512, 2 k-tiles/split)
// pgh[ks][b][j] = sum_{c in ks-split} WtH[c][j]*h[b][c]         (K=256, 1 k-tile/split)
// grid = dim3(12 j-tiles, 4 k-splits), block = 256
__global__ __launch_bounds__(256) void k2a_gates(
    const float* __restrict__ ctx_raw, const float* __restrict__ h,
    const float* __restrict__ WtA, const float* __restrict__ WtH,
    float* __restrict__ pgi, float* __restrict__ pgh) {
  __shared__ __align__(16) float wlds[64][64];   // [k][j]
  __shared__ __align__(16) float clds[32][64];   // [b][k]
  const int t = threadIdx.x;
  const int j0 = blockIdx.x * 64;
  const int ks = blockIdx.y;
  const int jl = (t & 31) * 2;        // 2 j's per thread
  const int b0 = (t >> 5) * 4;        // 4 b's per thread

  float acc[2][4] = {};
  // ---- gi: k in [ks*128, ks*128+128), two 64-tiles ----
#pragma unroll
  for (int kt = 0; kt < 2; ++kt) {
    const int k0 = ks * 128 + kt * 64;
    __syncthreads();
#pragma unroll
    for (int q = 0; q < 4; ++q) {        // stage W slice: 64 rows x 16 float4
      int idx = q * 256 + t; int r = idx >> 4, f4 = (idx & 15) * 4;
      *(float4*)&wlds[r][f4] = *(const float4*)&WtA[(size_t)(k0 + r) * G3_ + j0 + f4];
    }
#pragma unroll
    for (int q = 0; q < 2; ++q) {        // stage ctx slice: 32 rows x 16 float4
      int idx = q * 256 + t; int bb = idx >> 4, f4 = (idx & 15) * 4;
      *(float4*)&clds[bb][f4] = *(const float4*)&ctx_raw[(size_t)bb * C_ + k0 + f4];
    }
    __syncthreads();
#pragma unroll 8
    for (int k = 0; k < 64; ++k) {
      float w0 = wlds[k][jl], w1 = wlds[k][jl + 1];
      float x0 = clds[b0][k], x1 = clds[b0 + 1][k], x2 = clds[b0 + 2][k], x3 = clds[b0 + 3][k];
      acc[0][0] += w0 * x0; acc[0][1] += w0 * x1; acc[0][2] += w0 * x2; acc[0][3] += w0 * x3;
      acc[1][0] += w1 * x0; acc[1][1] += w1 * x1; acc[1][2] += w1 * x2; acc[1][3] += w1 * x3;
    }
  }
#pragma unroll
  for (int i = 0; i < 2; ++i)
#pragma unroll
    for (int q = 0; q < 4; ++q)
      pgi[((size_t)ks * B_ + b0 + q) * G3_ + j0 + jl + i] = acc[i][q];

  // ---- gh: k in [ks*64, ks*64+64), one tile ----
  float acb[2][4] = {};
  {
    const int k0 = ks * 64;
    __syncthreads();
#pragma unroll
    for (int q = 0; q < 4; ++q) {        // 64 rows x 16 float4
      int idx = q * 256 + t; int r = idx >> 4, f4 = (idx & 15) * 4;
      *(float4*)&wlds[r][f4] = *(const float4*)&WtH[(size_t)(k0 + r) * G3_ + j0 + f4];
    }
#pragma unroll
    for (int q = 0; q < 2; ++q) {        // 32 rows x 16 float4
      int idx = q * 256 + t; int bb = idx >> 4, f4 = (idx & 15) * 4;
      *(float4*)&clds[bb][f4] = *(const float4*)&h[(size_t)bb * H_ + k0 + f4];
    }
    __syncthreads();
#pragma unroll 8
    for (int k = 0; k < 64; ++k) {
      float w0 = wlds[k][jl], w1 = wlds[k][jl + 1];
      float x0 = clds[b0][k], x1 = clds[b0 + 1][k], x2 = clds[b0 + 2][k], x3 = clds[b0 + 3][k];
      acb[0][0] += w0 * x0; acb[0][1] += w0 * x1; acb[0][2] += w0 * x2; acb[0][3] += w0 * x3;
      acb[1][0] += w1 * x0; acb[1][1] += w1 * x1; acb[1][2] += w1 * x2; acb[1][3] += w1 * x3;
    }
  }
#pragma unroll
  for (int i = 0; i < 2; ++i)
#pragma unroll
    for (int q = 0; q < 4; ++q)
      pgh[((size_t)ks * B_ + b0 + q) * G3_ + j0 + jl + i] = acb[i][q];
}

// ---------------- K2b: per-b tail. grid = 32, block = 512 ----------------
__global__ __launch_bounds__(512) void k2b_tail(
    int tstep,
    const float* __restrict__ pgi, const float* __restrict__ pgh,
    const float* __restrict__ l_total_c,
    const float* __restrict__ WtO,
    const float* __restrict__ b_gru_ih, const float* __restrict__ b_gru_hh,
    const float* __restrict__ Wt_s1, const float* __restrict__ b_s1,
    const float* __restrict__ Wt_h2h, const float* __restrict__ b_h2h,
    const float* __restrict__ w_s2, const float* __restrict__ b_s2,
    float* __restrict__ h, float* __restrict__ pp, int* __restrict__ pre,
    float* __restrict__ ctx_raw, float* __restrict__ l_total,
    float* __restrict__ out) {
  __shared__ __align__(16) float shn[H_];
  __shared__ __align__(16) float ss1[H_];
  __shared__ float sst[64];
  const int b = blockIdx.x;
  const int t = threadIdx.x;
  const int prev = pre[b];
  const float invl = 1.0f / l_total_c[b];

  if (t < H_) {
    float gi0 = 0.f, gi1 = 0.f, gi2 = 0.f, gh0 = 0.f, gh1 = 0.f, gh2 = 0.f;
#pragma unroll
    for (int ks = 0; ks < 4; ++ks) {
      const float* pg = pgi + ((size_t)ks * B_ + b) * G3_;
      const float* ph = pgh + ((size_t)ks * B_ + b) * G3_;
      gi0 += pg[t]; gi1 += pg[t + 256]; gi2 += pg[t + 512];
      gh0 += ph[t]; gh1 += ph[t + 256]; gh2 += ph[t + 512];
    }
    const float* wo = WtO + (size_t)prev * G3_;
    gi0 = gi0 * invl + b_gru_ih[t]       + wo[t];
    gi1 = gi1 * invl + b_gru_ih[t + 256] + wo[t + 256];
    gi2 = gi2 * invl + b_gru_ih[t + 512] + wo[t + 512];
    gh0 += b_gru_hh[t]; gh1 += b_gru_hh[t + 256]; gh2 += b_gru_hh[t + 512];
    const float h_old = h[b * H_ + t];
    const float r = fast_sigmoid(gi0 + gh0);
    const float z = fast_sigmoid(gi1 + gh1);
    const float nn = fast_tanh(gi2 + r * gh2);
    const float hnew = (1.0f - z) * nn + z * h_old;
    h[b * H_ + t] = hnew;
    shn[t] = hnew;
  }
  // reset accumulators for next step (K2a already consumed them)
  ctx_raw[b * C_ + t] = 0.0f;
  if (t == 0) l_total[b] = 0.0f;
  __syncthreads();

  if (t < H_) {
    float acc = b_s1[t];
    const float* w1 = Wt_s1 + t;
#pragma unroll 8
    for (int c = 0; c < H_; ++c) acc += w1[(size_t)c * H_] * shn[c];
    ss1[t] = acc;
  } else if (t < 2 * H_) {
    const int tt = t - H_;
    float acc = b_h2h[tt];
    const float* wh2 = Wt_h2h + tt;
#pragma unroll 8
    for (int c = 0; c < H_; ++c) acc += wh2[(size_t)c * H_] * shn[c];
    pp[b * H_ + tt] = acc;
  }
  __syncthreads();

  const int wv = t >> 6, lane = t & 63;
  for (int v = wv; v < V_; v += 8) {
    float4 wr = *(const float4*)&w_s2[(size_t)v * H_ + lane * 4];
    float4 sv = *(const float4*)&ss1[lane * 4];
    float acc = wr.x * sv.x + wr.y * sv.y + wr.z * sv.z + wr.w * sv.w;
#pragma unroll
    for (int off = 32; off > 0; off >>= 1) acc += __shfl_xor(acc, off);
    if (lane == 0) sst[v] = acc + b_s2[v];
  }
  __syncthreads();

  if (t < 64) {
    float val = (lane < V_) ? sst[lane] : -INFINITY;
    float m = val;
#pragma unroll
    for (int off = 32; off > 0; off >>= 1) m = fmaxf(m, __shfl_xor(m, off));
    unsigned long long msk = __ballot(val == m);
    int amax = __ffsll(msk) - 1;   // first index achieving max (matches jnp.argmax)
    float e = (lane < V_) ? __expf(val - m) : 0.0f;
    float ssum = e;
#pragma unroll
    for (int off = 32; off > 0; off >>= 1) ssum += __shfl_xor(ssum, off);
    if (lane < V_) out[((size_t)b * T_ + tstep) * V_ + lane] = e / ssum;
    if (lane == 0) pre[b] = amax;
  }
}

extern "C" void kernel_launch(void* const* d_in, const int* in_sizes, int n_in,
                              void* d_out, int out_size, void* d_ws, size_t ws_size,
                              hipStream_t stream) {
  (void)in_sizes; (void)n_in; (void)out_size; (void)ws_size;
  const float* feat     = (const float*)d_in[0];
  const float* w_i2h    = (const float*)d_in[1];
  const float* w_h2h    = (const float*)d_in[2];
  const float* b_h2h    = (const float*)d_in[3];
  const float* w_score  = (const float*)d_in[4];
  const float* w_gru_ih = (const float*)d_in[5];
  const float* w_gru_hh = (const float*)d_in[6];
  const float* b_gru_ih = (const float*)d_in[7];
  const float* b_gru_hh = (const float*)d_in[8];
  const float* w_s1     = (const float*)d_in[9];
  const float* b_s1     = (const float*)d_in[10];
  const float* w_s2     = (const float*)d_in[11];
  const float* b_s2     = (const float*)d_in[12];
  float* out = (float*)d_out;

  char* ws = (char*)d_ws;
  size_t off = 0;
  auto alloc = [&](size_t bytes) { void* p = ws + off; off += (bytes + 255) & ~(size_t)255; return p; };
  float* fp       = (float*)alloc((size_t)B_ * N_ * H_ * 4);        // 33.55 MB
  float* ctx_raw  = (float*)alloc((size_t)B_ * C_ * 4);             // 64 KB (atomic accumulators)
  float* l_total  = (float*)alloc((size_t)B_ * 4);
  float* pgi      = (float*)alloc((size_t)4 * B_ * G3_ * 4);        // 393 KB
  float* pgh      = (float*)alloc((size_t)4 * B_ * G3_ * 4);
  float* WtA      = (float*)alloc((size_t)C_ * G3_ * 4);            // 1.57 MB  [c][j]
  float* WtO      = (float*)alloc((size_t)V_ * G3_ * 4);            //           [v][j]
  float* WtH      = (float*)alloc((size_t)H_ * G3_ * 4);            // 786 KB   [c][j]
  float* Wt_s1    = (float*)alloc((size_t)H_ * H_ * 4);
  float* Wt_h2h   = (float*)alloc((size_t)H_ * H_ * 4);
  float* h        = (float*)alloc((size_t)B_ * H_ * 4);
  float* pp       = (float*)alloc((size_t)B_ * H_ * 4);
  int*   pre      = (int*)alloc((size_t)B_ * 4);

  init_kernel<<<64, 256, 0, stream>>>(b_h2h, h, pp, pre, ctx_raw, l_total);
  fp_gemm<<<dim3((B_ * N_) / 64, H_ / 64), 256, 0, stream>>>(feat, w_i2h, fp);
  transpose_split<<<(G3_ * CV_ + 255) / 256, 256, 0, stream>>>(w_gru_ih, WtA, WtO, G3_, CV_, C_);
  transpose_split<<<(G3_ * H_ + 255) / 256, 256, 0, stream>>>(w_gru_hh, WtH, WtH, G3_, H_, H_);
  transpose_split<<<(H_ * H_ + 255) / 256, 256, 0, stream>>>(w_s1, Wt_s1, Wt_s1, H_, H_, H_);
  transpose_split<<<(H_ * H_ + 255) / 256, 256, 0, stream>>>(w_h2h, Wt_h2h, Wt_h2h, H_, H_, H_);

  for (int tstep = 0; tstep < T_; ++tstep) {
    k1_attn<<<B_ * CHUNKS_, 256, 0, stream>>>(feat, fp, w_score, pp, ctx_raw, l_total);
    k2a_gates<<<dim3(12, 4), 256, 0, stream>>>(ctx_raw, h, WtA, WtH, pgi, pgh);
    k2b_tail<<<B_, 512, 0, stream>>>(tstep, pgi, pgh, l_total, WtO,
                                     b_gru_ih, b_gru_hh, Wt_s1, b_s1, Wt_h2h, b_h2h,
                                     w_s2, b_s2, h, pp, pre, ctx_raw, l_total, out);
  }
}

// Round 8
// 17575.063 us; speedup vs baseline: 10.6523x; 1.1652x over previous
//
#include <hip/hip_runtime.h>
#include <math.h>

#define B_ 32
#define N_ 1024
#define C_ 512
#define H_ 256
#define V_ 50
#define T_ 501
#define CV_ 562     // C + V
#define G3_ 768     // 3*H
#define CHUNKS_ 32  // K1 blocks per batch row
#define POSB_ 32    // positions per K1 block

typedef float    f32x4 __attribute__((ext_vector_type(4)));
typedef _Float16 f16x4 __attribute__((ext_vector_type(4)));
typedef _Float16 f16x8 __attribute__((ext_vector_type(8)));

__device__ __forceinline__ float fast_rcp(float x) { return __builtin_amdgcn_rcpf(x); }
__device__ __forceinline__ float fast_tanh(float x) {
  float e = __expf(2.0f * x);
  return 1.0f - 2.0f * fast_rcp(e + 1.0f);
}
__device__ __forceinline__ float fast_sigmoid(float x) {
  return fast_rcp(1.0f + __expf(-x));
}

// ---------------- feat_proj GEMM: FPh[m][h] = fp16( sum_c A[m][c] * W[h][c] ) ----------------
__global__ __launch_bounds__(256) void fp_gemm(const float* __restrict__ A,
                                               const float* __restrict__ W,
                                               _Float16* __restrict__ FPh) {
  __shared__ __align__(16) float As[16][68];
  __shared__ __align__(16) float Ws[16][68];
  const int t = threadIdx.x;
  const int m0 = blockIdx.x * 64;
  const int h0 = blockIdx.y * 64;
  const int lr = t & 63;
  const int kg = t >> 6;
  const int tx = t & 15, ty = t >> 4;
  float acc[4][4] = {};
  for (int k0 = 0; k0 < C_; k0 += 16) {
    float4 av = *(const float4*)&A[(size_t)(m0 + lr) * C_ + k0 + kg * 4];
    float4 wv = *(const float4*)&W[(size_t)(h0 + lr) * C_ + k0 + kg * 4];
    As[kg*4+0][lr] = av.x; As[kg*4+1][lr] = av.y; As[kg*4+2][lr] = av.z; As[kg*4+3][lr] = av.w;
    Ws[kg*4+0][lr] = wv.x; Ws[kg*4+1][lr] = wv.y; Ws[kg*4+2][lr] = wv.z; Ws[kg*4+3][lr] = wv.w;
    __syncthreads();
#pragma unroll
    for (int kk = 0; kk < 16; ++kk) {
      float4 a = *(const float4*)&As[kk][ty * 4];
      float4 w = *(const float4*)&Ws[kk][tx * 4];
      acc[0][0] += a.x*w.x; acc[0][1] += a.x*w.y; acc[0][2] += a.x*w.z; acc[0][3] += a.x*w.w;
      acc[1][0] += a.y*w.x; acc[1][1] += a.y*w.y; acc[1][2] += a.y*w.z; acc[1][3] += a.y*w.w;
      acc[2][0] += a.z*w.x; acc[2][1] += a.z*w.y; acc[2][2] += a.z*w.z; acc[2][3] += a.z*w.w;
      acc[3][0] += a.w*w.x; acc[3][1] += a.w*w.y; acc[3][2] += a.w*w.z; acc[3][3] += a.w*w.w;
    }
    __syncthreads();
  }
#pragma unroll
  for (int i = 0; i < 4; ++i) {
    f16x4 o;
    o.x = (_Float16)acc[i][0]; o.y = (_Float16)acc[i][1];
    o.z = (_Float16)acc[i][2]; o.w = (_Float16)acc[i][3];
    *(f16x4*)&FPh[(size_t)(m0 + ty*4 + i) * H_ + h0 + tx*4] = o;
  }
}

// ---------------- feat -> fp16 (one-time) ----------------
__global__ void feat_to_fp16(const float* __restrict__ src, _Float16* __restrict__ dst,
                             int total4) {
  int i = blockIdx.x * 256 + threadIdx.x;
  if (i >= total4) return;
  f32x4 v = *(const f32x4*)&src[(size_t)i * 4];
  f16x4 o; o.x = (_Float16)v.x; o.y = (_Float16)v.y; o.z = (_Float16)v.z; o.w = (_Float16)v.w;
  *(f16x4*)&dst[(size_t)i * 4] = o;
}

// ---------------- weight transpose (one-time): dstA[c][j] = src[j][c] for c<splitc, rest -> dstB ----------------
__global__ void transpose_split(const float* __restrict__ src, float* __restrict__ dstA,
                                float* __restrict__ dstB, int rows, int cols, int splitc) {
  int i = blockIdx.x * 256 + threadIdx.x;
  if (i >= rows * cols) return;
  int j = i / cols, c = i - j * cols;
  float v = src[i];
  if (c < splitc) dstA[(size_t)c * rows + j] = v;
  else            dstB[(size_t)(c - splitc) * rows + j] = v;
}

// ---------------- init: h=0, pp=b_h2h, pre=0, ctx_raw=0, l_total=0 ----------------
__global__ void init_kernel(const float* __restrict__ b_h2h, float* __restrict__ h,
                            float* __restrict__ pp, int* __restrict__ pre,
                            float* __restrict__ ctx_raw, float* __restrict__ l_total) {
  int i = blockIdx.x * blockDim.x + threadIdx.x;
  if (i < B_ * H_) { h[i] = 0.0f; pp[i] = b_h2h[i & (H_ - 1)]; }
  if (i < B_ * C_) ctx_raw[i] = 0.0f;
  if (i < B_) { pre[i] = 0; l_total[i] = 0.0f; }
}

// ---------------- K1: attention scores -> exp -> partial ctx -> atomic accumulate ----------------
// grid = B*CHUNKS blocks, block = 256 (4 waves, 8 positions each). fp16 streams, nt loads.
__global__ __launch_bounds__(256) void k1_attn(
    const _Float16* __restrict__ feath, const _Float16* __restrict__ fph,
    const float* __restrict__ w_score, const float* __restrict__ pp,
    float* __restrict__ ctx_raw, float* __restrict__ l_total) {
  __shared__ __align__(16) float lds_ctx[4 * C_];
  __shared__ float lds_l[4];

  const int t = threadIdx.x;
  const int wv = t >> 6;
  const int lane = t & 63;
  const int b = blockIdx.x >> 5;        // / CHUNKS_
  const int chunk = blockIdx.x & (CHUNKS_ - 1);

  float4 ppr = *(const float4*)&pp[b * H_ + lane * 4];
  float4 wsr = *(const float4*)&w_score[lane * 4];
  float aA0 = 0.f, aA1 = 0.f, aA2 = 0.f, aA3 = 0.f;
  float aB0 = 0.f, aB1 = 0.f, aB2 = 0.f, aB3 = 0.f;
  float lacc = 0.f;
  const _Float16* fphb = fph + (size_t)b * N_ * H_;
  const _Float16* fbb  = feath + (size_t)b * N_ * C_;
  const int n0 = chunk * POSB_ + wv * 8;
#pragma unroll 2
  for (int i = 0; i < 8; ++i) {
    const int n = n0 + i;
    f16x4 v = __builtin_nontemporal_load((const f16x4*)&fphb[(size_t)n * H_ + lane * 4]);
    float s = fast_tanh((float)v.x + ppr.x) * wsr.x + fast_tanh((float)v.y + ppr.y) * wsr.y
            + fast_tanh((float)v.z + ppr.z) * wsr.z + fast_tanh((float)v.w + ppr.w) * wsr.w;
#pragma unroll
    for (int off = 32; off > 0; off >>= 1) s += __shfl_xor(s, off);
    float p = __expf(s);   // |s| <= sum|w_score| ~ 10 -> safe without max-subtraction
    lacc += p;
    f16x8 f = __builtin_nontemporal_load((const f16x8*)&fbb[(size_t)n * C_ + lane * 8]);
    aA0 += p * (float)f.s0; aA1 += p * (float)f.s1; aA2 += p * (float)f.s2; aA3 += p * (float)f.s3;
    aB0 += p * (float)f.s4; aB1 += p * (float)f.s5; aB2 += p * (float)f.s6; aB3 += p * (float)f.s7;
  }
  {
    float4 o0; o0.x = aA0; o0.y = aA1; o0.z = aA2; o0.w = aA3;
    float4 o1; o1.x = aB0; o1.y = aB1; o1.z = aB2; o1.w = aB3;
    *(float4*)&lds_ctx[wv * C_ + lane * 8] = o0;
    *(float4*)&lds_ctx[wv * C_ + lane * 8 + 4] = o1;
  }
  if (lane == 0) lds_l[wv] = lacc;
  __syncthreads();
  {
    float c0 = lds_ctx[t] + lds_ctx[C_ + t] + lds_ctx[2 * C_ + t] + lds_ctx[3 * C_ + t];
    float c1 = lds_ctx[t + 256] + lds_ctx[C_ + t + 256] + lds_ctx[2 * C_ + t + 256] + lds_ctx[3 * C_ + t + 256];
    unsafeAtomicAdd(&ctx_raw[b * C_ + t], c0);
    unsafeAtomicAdd(&ctx_raw[b * C_ + t + 256], c1);
    if (t == 0) unsafeAtomicAdd(&l_total[b], lds_l[0] + lds_l[1] + lds_l[2] + lds_l[3]);
  }
}

// ---------------- K2a: gate GEMM (weights read ONCE per step) ----------------
// grid = dim3(12 j-tiles, 4 k-splits), block = 256
__global__ __launch_bounds__(256) void k2a_gates(
    const float* __restrict__ ctx_raw, const float* __restrict__ h,
    const float* __restrict__ WtA, const float* __restrict__ WtH,
    float* __restrict__ pgi, float* __restrict__ pgh) {
  __shared__ __align__(16) float wlds[64][64];   // [k][j]
  __shared__ __align__(16) float clds[32][64];   // [b][k]
  const int t = threadIdx.x;
  const int j0 = blockIdx.x * 64;
  const int ks = blockIdx.y;
  const int jl = (t & 31) * 2;        // 2 j's per thread
  const int b0 = (t >> 5) * 4;        // 4 b's per thread

  float acc[2][4] = {};
  // ---- gi: k in [ks*128, ks*128+128), two 64-tiles ----
#pragma unroll
  for (int kt = 0; kt < 2; ++kt) {
    const int k0 = ks * 128 + kt * 64;
    __syncthreads();
#pragma unroll
    for (int q = 0; q < 4; ++q) {        // stage W slice: 64 rows x 16 float4
      int idx = q * 256 + t; int r = idx >> 4, f4 = (idx & 15) * 4;
      *(float4*)&wlds[r][f4] = *(const float4*)&WtA[(size_t)(k0 + r) * G3_ + j0 + f4];
    }
#pragma unroll
    for (int q = 0; q < 2; ++q) {        // stage ctx slice: 32 rows x 16 float4
      int idx = q * 256 + t; int bb = idx >> 4, f4 = (idx & 15) * 4;
      *(float4*)&clds[bb][f4] = *(const float4*)&ctx_raw[(size_t)bb * C_ + k0 + f4];
    }
    __syncthreads();
#pragma unroll 8
    for (int k = 0; k < 64; ++k) {
      float w0 = wlds[k][jl], w1 = wlds[k][jl + 1];
      float x0 = clds[b0][k], x1 = clds[b0 + 1][k], x2 = clds[b0 + 2][k], x3 = clds[b0 + 3][k];
      acc[0][0] += w0 * x0; acc[0][1] += w0 * x1; acc[0][2] += w0 * x2; acc[0][3] += w0 * x3;
      acc[1][0] += w1 * x0; acc[1][1] += w1 * x1; acc[1][2] += w1 * x2; acc[1][3] += w1 * x3;
    }
  }
#pragma unroll
  for (int i = 0; i < 2; ++i)
#pragma unroll
    for (int q = 0; q < 4; ++q)
      pgi[((size_t)ks * B_ + b0 + q) * G3_ + j0 + jl + i] = acc[i][q];

  // ---- gh: k in [ks*64, ks*64+64), one tile ----
  float acb[2][4] = {};
  {
    const int k0 = ks * 64;
    __syncthreads();
#pragma unroll
    for (int q = 0; q < 4; ++q) {        // 64 rows x 16 float4
      int idx = q * 256 + t; int r = idx >> 4, f4 = (idx & 15) * 4;
      *(float4*)&wlds[r][f4] = *(const float4*)&WtH[(size_t)(k0 + r) * G3_ + j0 + f4];
    }
#pragma unroll
    for (int q = 0; q < 2; ++q) {        // 32 rows x 16 float4
      int idx = q * 256 + t; int bb = idx >> 4, f4 = (idx & 15) * 4;
      *(float4*)&clds[bb][f4] = *(const float4*)&h[(size_t)bb * H_ + k0 + f4];
    }
    __syncthreads();
#pragma unroll 8
    for (int k = 0; k < 64; ++k) {
      float w0 = wlds[k][jl], w1 = wlds[k][jl + 1];
      float x0 = clds[b0][k], x1 = clds[b0 + 1][k], x2 = clds[b0 + 2][k], x3 = clds[b0 + 3][k];
      acb[0][0] += w0 * x0; acb[0][1] += w0 * x1; acb[0][2] += w0 * x2; acb[0][3] += w0 * x3;
      acb[1][0] += w1 * x0; acb[1][1] += w1 * x1; acb[1][2] += w1 * x2; acb[1][3] += w1 * x3;
    }
  }
#pragma unroll
  for (int i = 0; i < 2; ++i)
#pragma unroll
    for (int q = 0; q < 4; ++q)
      pgh[((size_t)ks * B_ + b0 + q) * G3_ + j0 + jl + i] = acb[i][q];
}

// ---------------- K2b: per-b tail. grid = 32, block = 512 ----------------
__global__ __launch_bounds__(512) void k2b_tail(
    int tstep,
    const float* __restrict__ pgi, const float* __restrict__ pgh,
    const float* __restrict__ l_total_c,
    const float* __restrict__ WtO,
    const float* __restrict__ b_gru_ih, const float* __restrict__ b_gru_hh,
    const float* __restrict__ Wt_s1, const float* __restrict__ b_s1,
    const float* __restrict__ Wt_h2h, const float* __restrict__ b_h2h,
    const float* __restrict__ w_s2, const float* __restrict__ b_s2,
    float* __restrict__ h, float* __restrict__ pp, int* __restrict__ pre,
    float* __restrict__ ctx_raw, float* __restrict__ l_total,
    float* __restrict__ out) {
  __shared__ __align__(16) float shn[H_];
  __shared__ __align__(16) float ss1[H_];
  __shared__ float sst[64];
  const int b = blockIdx.x;
  const int t = threadIdx.x;
  const int prev = pre[b];
  const float invl = 1.0f / l_total_c[b];

  if (t < H_) {
    float gi0 = 0.f, gi1 = 0.f, gi2 = 0.f, gh0 = 0.f, gh1 = 0.f, gh2 = 0.f;
#pragma unroll
    for (int ks = 0; ks < 4; ++ks) {
      const float* pg = pgi + ((size_t)ks * B_ + b) * G3_;
      const float* ph = pgh + ((size_t)ks * B_ + b) * G3_;
      gi0 += pg[t]; gi1 += pg[t + 256]; gi2 += pg[t + 512];
      gh0 += ph[t]; gh1 += ph[t + 256]; gh2 += ph[t + 512];
    }
    const float* wo = WtO + (size_t)prev * G3_;
    gi0 = gi0 * invl + b_gru_ih[t]       + wo[t];
    gi1 = gi1 * invl + b_gru_ih[t + 256] + wo[t + 256];
    gi2 = gi2 * invl + b_gru_ih[t + 512] + wo[t + 512];
    gh0 += b_gru_hh[t]; gh1 += b_gru_hh[t + 256]; gh2 += b_gru_hh[t + 512];
    const float h_old = h[b * H_ + t];
    const float r = fast_sigmoid(gi0 + gh0);
    const float z = fast_sigmoid(gi1 + gh1);
    const float nn = fast_tanh(gi2 + r * gh2);
    const float hnew = (1.0f - z) * nn + z * h_old;
    h[b * H_ + t] = hnew;
    shn[t] = hnew;
  }
  // reset accumulators for next step (K2a already consumed them)
  ctx_raw[b * C_ + t] = 0.0f;
  if (t == 0) l_total[b] = 0.0f;
  __syncthreads();

  if (t < H_) {
    float acc = b_s1[t];
    const float* w1 = Wt_s1 + t;
#pragma unroll 8
    for (int c = 0; c < H_; ++c) acc += w1[(size_t)c * H_] * shn[c];
    ss1[t] = acc;
  } else if (t < 2 * H_) {
    const int tt = t - H_;
    float acc = b_h2h[tt];
    const float* wh2 = Wt_h2h + tt;
#pragma unroll 8
    for (int c = 0; c < H_; ++c) acc += wh2[(size_t)c * H_] * shn[c];
    pp[b * H_ + tt] = acc;
  }
  __syncthreads();

  const int wv = t >> 6, lane = t & 63;
  for (int v = wv; v < V_; v += 8) {
    float4 wr = *(const float4*)&w_s2[(size_t)v * H_ + lane * 4];
    float4 sv = *(const float4*)&ss1[lane * 4];
    float acc = wr.x * sv.x + wr.y * sv.y + wr.z * sv.z + wr.w * sv.w;
#pragma unroll
    for (int off = 32; off > 0; off >>= 1) acc += __shfl_xor(acc, off);
    if (lane == 0) sst[v] = acc + b_s2[v];
  }
  __syncthreads();

  if (t < 64) {
    float val = (lane < V_) ? sst[lane] : -INFINITY;
    float m = val;
#pragma unroll
    for (int off = 32; off > 0; off >>= 1) m = fmaxf(m, __shfl_xor(m, off));
    unsigned long long msk = __ballot(val == m);
    int amax = __ffsll(msk) - 1;   // first index achieving max (matches jnp.argmax)
    float e = (lane < V_) ? __expf(val - m) : 0.0f;
    float ssum = e;
#pragma unroll
    for (int off = 32; off > 0; off >>= 1) ssum += __shfl_xor(ssum, off);
    if (lane < V_) out[((size_t)b * T_ + tstep) * V_ + lane] = e / ssum;
    if (lane == 0) pre[b] = amax;
  }
}

extern "C" void kernel_launch(void* const* d_in, const int* in_sizes, int n_in,
                              void* d_out, int out_size, void* d_ws, size_t ws_size,
                              hipStream_t stream) {
  (void)in_sizes; (void)n_in; (void)out_size; (void)ws_size;
  const float* feat     = (const float*)d_in[0];
  const float* w_i2h    = (const float*)d_in[1];
  const float* w_h2h    = (const float*)d_in[2];
  const float* b_h2h    = (const float*)d_in[3];
  const float* w_score  = (const float*)d_in[4];
  const float* w_gru_ih = (const float*)d_in[5];
  const float* w_gru_hh = (const float*)d_in[6];
  const float* b_gru_ih = (const float*)d_in[7];
  const float* b_gru_hh = (const float*)d_in[8];
  const float* w_s1     = (const float*)d_in[9];
  const float* b_s1     = (const float*)d_in[10];
  const float* w_s2     = (const float*)d_in[11];
  const float* b_s2     = (const float*)d_in[12];
  float* out = (float*)d_out;

  char* ws = (char*)d_ws;
  size_t off = 0;
  auto alloc = [&](size_t bytes) { void* p = ws + off; off += (bytes + 255) & ~(size_t)255; return p; };
  _Float16* fph   = (_Float16*)alloc((size_t)B_ * N_ * H_ * 2);   // 16.8 MB fp16
  _Float16* feath = (_Float16*)alloc((size_t)B_ * N_ * C_ * 2);   // 33.6 MB fp16
  float* ctx_raw  = (float*)alloc((size_t)B_ * C_ * 4);
  float* l_total  = (float*)alloc((size_t)B_ * 4);
  float* pgi      = (float*)alloc((size_t)4 * B_ * G3_ * 4);
  float* pgh      = (float*)alloc((size_t)4 * B_ * G3_ * 4);
  float* WtA      = (float*)alloc((size_t)C_ * G3_ * 4);          // [c][j]
  float* WtO      = (float*)alloc((size_t)V_ * G3_ * 4);          // [v][j]
  float* WtH      = (float*)alloc((size_t)H_ * G3_ * 4);          // [c][j]
  float* Wt_s1    = (float*)alloc((size_t)H_ * H_ * 4);
  float* Wt_h2h   = (float*)alloc((size_t)H_ * H_ * 4);
  float* h        = (float*)alloc((size_t)B_ * H_ * 4);
  float* pp       = (float*)alloc((size_t)B_ * H_ * 4);
  int*   pre      = (int*)alloc((size_t)B_ * 4);

  init_kernel<<<64, 256, 0, stream>>>(b_h2h, h, pp, pre, ctx_raw, l_total);
  fp_gemm<<<dim3((B_ * N_) / 64, H_ / 64), 256, 0, stream>>>(feat, w_i2h, fph);
  feat_to_fp16<<<(B_ * N_ * C_ / 4 + 255) / 256, 256, 0, stream>>>(feat, feath, B_ * N_ * C_ / 4);
  transpose_split<<<(G3_ * CV_ + 255) / 256, 256, 0, stream>>>(w_gru_ih, WtA, WtO, G3_, CV_, C_);
  transpose_split<<<(G3_ * H_ + 255) / 256, 256, 0, stream>>>(w_gru_hh, WtH, WtH, G3_, H_, H_);
  transpose_split<<<(H_ * H_ + 255) / 256, 256, 0, stream>>>(w_s1, Wt_s1, Wt_s1, H_, H_, H_);
  transpose_split<<<(H_ * H_ + 255) / 256, 256, 0, stream>>>(w_h2h, Wt_h2h, Wt_h2h, H_, H_, H_);

  for (int tstep = 0; tstep < T_; ++tstep) {
    k1_attn<<<B_ * CHUNKS_, 256, 0, stream>>>(feath, fph, w_score, pp, ctx_raw, l_total);
    k2a_gates<<<dim3(12, 4), 256, 0, stream>>>(ctx_raw, h, WtA, WtH, pgi, pgh);
    k2b_tail<<<B_, 512, 0, stream>>>(tstep, pgi, pgh, l_total, WtO,
                                     b_gru_ih, b_gru_hh, Wt_s1, b_s1, Wt_h2h, b_h2h,
                                     w_s2, b_s2, h, pp, pre, ctx_raw, l_total, out);
  }
}